// Round 1
// 823.168 us; speedup vs baseline: 1.0896x; 1.0896x over previous
//
#include <hip/hip_runtime.h>
#include <hip/hip_bf16.h>

// ---------- helpers ----------
typedef __bf16 bf16x8 __attribute__((ext_vector_type(8)));
typedef float  f32x4  __attribute__((ext_vector_type(4)));

__device__ __forceinline__ unsigned short f2bf(float f) {
    union { float f; unsigned int u; } v; v.f = f;
    unsigned int u = v.u;
    unsigned int r = (u + 0x7fffu + ((u >> 16) & 1u)) >> 16;   // RNE
    return (unsigned short)r;
}

typedef const __attribute__((address_space(1))) unsigned int* gptr_t;
typedef __attribute__((address_space(3))) unsigned int* lptr_t;
__device__ __forceinline__ void async_ld16(const void* g, void* l) {
    __builtin_amdgcn_global_load_lds((gptr_t)g, (lptr_t)l, 16, 0, 0);
}

// fast GELU (tanh form): x * sigmoid(2*sqrt(2/pi)*(x + 0.044715 x^3))
// max |err| vs exact-erf GELU ~5e-4; 8 VALU + exp2 + rcp.
__device__ __forceinline__ float gelu_fast(float x) {
    const float c1 = 2.30223608f;          // 2*sqrt(2/pi)*log2(e)
    const float c2 = 0.102944903f;         // c1 * 0.044715
    float s  = x * x;
    float zn = x * __builtin_fmaf(s, -c2, -c1);   // = -2t*log2e
    float u  = __builtin_amdgcn_exp2f(zn);        // e^{-2t}; ->inf for big -x (rcp->0, no NaN)
    return x * __builtin_amdgcn_rcpf(1.0f + u);
}

#define Bn 16384
#define Dd 1024
#define Hh 2048
#define Ee 4
#define Cc 3

// ---------- kernel 1: W1' = diag(ex_ln_g) * W1, transposed to [N=E*H][K=D], bf16 ----------
__global__ void prep_w1(const float* __restrict__ w1, const float* __restrict__ exlng,
                        unsigned short* __restrict__ w1t) {
    __shared__ float tile[64][65];
    const int d0 = blockIdx.x * 64, h0 = blockIdx.y * 64, e = blockIdx.z;
    const int t = threadIdx.x;
    const float* gp = exlng + e * Dd + d0;
    const float* wp = w1 + ((size_t)e * Dd + d0) * Hh + h0;
    #pragma unroll
    for (int j = 0; j < 16; ++j) {
        int idx = t + j * 256; int dl = idx >> 6, hl = idx & 63;
        tile[dl][hl] = wp[(size_t)dl * Hh + hl] * gp[dl];
    }
    __syncthreads();
    #pragma unroll
    for (int j = 0; j < 8; ++j) {
        int idx = t + j * 256; int hl = idx >> 5, k2 = (idx & 31) * 2;
        ushort2 o; o.x = f2bf(tile[k2][hl]); o.y = f2bf(tile[k2 + 1][hl]);
        *(ushort2*)(w1t + ((size_t)(e * Hh + h0 + hl)) * Dd + d0 + k2) = o;
    }
}

// ---------- kernel 2: b1'[n] = b1[e][h] + sum_d ex_ln_b[e][d] * W1[e][d][h] ----------
__global__ void prep_b1(const float* __restrict__ w1, const float* __restrict__ exlnb,
                        const float* __restrict__ b1, float* __restrict__ b1p) {
    const int e = blockIdx.y, h0 = blockIdx.x * 64;
    const int t = threadIdx.x, hl = t & 63, dq = t >> 6;
    float acc = 0.f;
    const float* wp = w1 + ((size_t)e * Dd) * Hh + h0 + hl;
    const float* lb = exlnb + e * Dd;
    for (int d = dq; d < Dd; d += 4)
        acc += lb[d] * wp[(size_t)d * Hh];
    __shared__ float red[4][64];
    red[dq][hl] = acc;
    __syncthreads();
    if (t < 64) {
        float s = red[0][t] + red[1][t] + red[2][t] + red[3][t];
        b1p[e * Hh + h0 + t] = b1[e * Hh + h0 + t] + s;
    }
}

// ---------- kernel 3: normalize + gate softmax + out init ----------
__global__ void norm_gate(const float* __restrict__ x,
                          const float* __restrict__ gg, const float* __restrict__ gb,
                          const float* __restrict__ gw, const float* __restrict__ gbias,
                          const float* __restrict__ b2,
                          unsigned short* __restrict__ normed,
                          float* __restrict__ gate, float* __restrict__ out) {
    const int b = blockIdx.x, t = threadIdx.x, w = t >> 6, lane = t & 63;
    float4 xv = ((const float4*)(x + (size_t)b * Dd))[t];
    float s = xv.x + xv.y + xv.z + xv.w;
    float q = xv.x * xv.x + xv.y * xv.y + xv.z * xv.z + xv.w * xv.w;
    for (int off = 32; off; off >>= 1) { s += __shfl_down(s, off); q += __shfl_down(q, off); }
    __shared__ float rs[4], rq[4], lg[4][4];
    if (lane == 0) { rs[w] = s; rq[w] = q; }
    __syncthreads();
    s = rs[0] + rs[1] + rs[2] + rs[3];
    q = rq[0] + rq[1] + rq[2] + rq[3];
    const float mu = s * (1.f / Dd);
    const float var = q * (1.f / Dd) - mu * mu;
    const float rstd = rsqrtf(var + 1e-5f);
    float n0 = (xv.x - mu) * rstd, n1 = (xv.y - mu) * rstd,
          n2 = (xv.z - mu) * rstd, n3 = (xv.w - mu) * rstd;
    ushort4 u; u.x = f2bf(n0); u.y = f2bf(n1); u.z = f2bf(n2); u.w = f2bf(n3);
    ((ushort4*)(normed + (size_t)b * Dd))[t] = u;
    // gate logits
    float4 g4 = ((const float4*)gg)[t], b4 = ((const float4*)gb)[t];
    float v0 = n0 * g4.x + b4.x, v1 = n1 * g4.y + b4.y,
          v2 = n2 * g4.z + b4.z, v3 = n3 * g4.w + b4.w;
    float4 w0 = ((const float4*)gw)[4 * t + 0], w1v = ((const float4*)gw)[4 * t + 1],
          w2v = ((const float4*)gw)[4 * t + 2], w3 = ((const float4*)gw)[4 * t + 3];
    float l0 = v0 * w0.x + v1 * w1v.x + v2 * w2v.x + v3 * w3.x;
    float l1 = v0 * w0.y + v1 * w1v.y + v2 * w2v.y + v3 * w3.y;
    float l2 = v0 * w0.z + v1 * w1v.z + v2 * w2v.z + v3 * w3.z;
    float l3 = v0 * w0.w + v1 * w1v.w + v2 * w2v.w + v3 * w3.w;
    for (int off = 32; off; off >>= 1) {
        l0 += __shfl_down(l0, off); l1 += __shfl_down(l1, off);
        l2 += __shfl_down(l2, off); l3 += __shfl_down(l3, off);
    }
    if (lane == 0) { lg[w][0] = l0; lg[w][1] = l1; lg[w][2] = l2; lg[w][3] = l3; }
    __syncthreads();
    if (t == 0) {
        float L0 = lg[0][0] + lg[1][0] + lg[2][0] + lg[3][0] + gbias[0];
        float L1 = lg[0][1] + lg[1][1] + lg[2][1] + lg[3][1] + gbias[1];
        float L2 = lg[0][2] + lg[1][2] + lg[2][2] + lg[3][2] + gbias[2];
        float L3 = lg[0][3] + lg[1][3] + lg[2][3] + lg[3][3] + gbias[3];
        float mx = fmaxf(fmaxf(L0, L1), fmaxf(L2, L3));
        float e0 = expf(L0 - mx), e1 = expf(L1 - mx), e2 = expf(L2 - mx), e3 = expf(L3 - mx);
        float inv = 1.f / (e0 + e1 + e2 + e3);
        float g0 = e0 * inv, g1 = e1 * inv, g2 = e2 * inv, g3 = e3 * inv;
        gate[b * 4 + 0] = g0; gate[b * 4 + 1] = g1;
        gate[b * 4 + 2] = g2; gate[b * 4 + 3] = g3;
        out[b * 3 + 0] = g0 * b2[0] + g1 * b2[3] + g2 * b2[6] + g3 * b2[9];
        out[b * 3 + 1] = g0 * b2[1] + g1 * b2[4] + g2 * b2[7] + g3 * b2[10];
        out[b * 3 + 2] = g0 * b2[2] + g1 * b2[5] + g2 * b2[8] + g3 * b2[11];
    }
}

// ---------- kernel 4: fused GEMM (normed @ W1') + GELU + (@W2) + gated atomic add ----------
// v2: XOR-swizzled LDS (linear gload_lds dest + pre-swizzled global src, swizzled ds_read),
//     double-buffered K-loop with counted vmcnt(4) + raw s_barrier, fast tanh-GELU.
__global__ __launch_bounds__(256) void gemm_fused(
    const unsigned short* __restrict__ A,    // [16384][1024] bf16
    const unsigned short* __restrict__ Bt,   // [8192][1024] bf16 (N-major)
    const float* __restrict__ b1p,           // [8192]
    const float* __restrict__ w2,            // [8192][3]
    const float* __restrict__ gate,          // [16384][4]
    float* __restrict__ out)                 // [16384][3]
{
    __shared__ unsigned short As[2][128 * 32];
    __shared__ unsigned short Bs[2][128 * 32];
    __shared__ float w2s[128 * 3];
    __shared__ float b1s[128];

    const int m0 = blockIdx.x * 128;
    const int n0 = blockIdx.y * 128;
    const int t = threadIdx.x, w = t >> 6, lane = t & 63;
    const int wm = w >> 1, wn = w & 1;
    const int quad = lane >> 4, l15 = lane & 15;

    if (t < 128) {
        b1s[t] = b1p[n0 + t];
        w2s[t * 3 + 0] = w2[(n0 + t) * 3 + 0];
        w2s[t * 3 + 1] = w2[(n0 + t) * 3 + 1];
        w2s[t * 3 + 2] = w2[(n0 + t) * 3 + 2];
    }

    // staging: wave w covers rows [w*32, w*32+32). Linear LDS dest (gload_lds requirement);
    // global source column pre-swizzled so LDS holds data at byte r*64 + (c ^ (((r>>1)&3)<<4)).
    const int scol = ((lane & 3) ^ ((lane >> 3) & 3)) * 8;
    const unsigned short* ga0 = A  + ((size_t)(m0 + w * 32 + (lane >> 2))) * Dd + scol;
    const unsigned short* gb0 = Bt + ((size_t)(n0 + w * 32 + (lane >> 2))) * Dd + scol;
    const int ldst = w * 1024 + lane * 8;     // element offset inside a buffer

    f32x4 acc[4][4] = {};

    // prologue: stage k-tile 0 into buffer 0
    async_ld16(ga0,            &As[0][ldst]);
    async_ld16(ga0 + 16 * Dd,  &As[0][ldst + 512]);
    async_ld16(gb0,            &Bs[0][ldst]);
    async_ld16(gb0 + 16 * Dd,  &Bs[0][ldst + 512]);

    const int rsw = (l15 >> 1) & 3;           // read-side swizzle (row bits 1..2)
    int cur = 0;
    #pragma unroll 2
    for (int k0 = 0; k0 < Dd; k0 += 32) {
        if (k0 + 32 < Dd) {
            const int nxt = cur ^ 1;
            async_ld16(ga0 + (k0 + 32),           &As[nxt][ldst]);
            async_ld16(ga0 + (k0 + 32) + 16 * Dd, &As[nxt][ldst + 512]);
            async_ld16(gb0 + (k0 + 32),           &Bs[nxt][ldst]);
            async_ld16(gb0 + (k0 + 32) + 16 * Dd, &Bs[nxt][ldst + 512]);
            __asm__ volatile("s_waitcnt vmcnt(4)" ::: "memory");  // tile-k0 loads landed; next 4 in flight
        } else {
            __asm__ volatile("s_waitcnt vmcnt(0)" ::: "memory");
        }
        __builtin_amdgcn_s_barrier();

        bf16x8 af[4], bfr[4];
        #pragma unroll
        for (int mi = 0; mi < 4; ++mi)
            af[mi] = *(const bf16x8*)(&As[cur][(wm * 64 + mi * 16 + l15) * 32 + (quad ^ rsw) * 8]);
        #pragma unroll
        for (int ni = 0; ni < 4; ++ni)
            bfr[ni] = *(const bf16x8*)(&Bs[cur][(wn * 64 + ni * 16 + l15) * 32 + (quad ^ rsw) * 8]);
        #pragma unroll
        for (int mi = 0; mi < 4; ++mi)
            #pragma unroll
            for (int ni = 0; ni < 4; ++ni)
                acc[mi][ni] = __builtin_amdgcn_mfma_f32_16x16x32_bf16(af[mi], bfr[ni], acc[mi][ni], 0, 0, 0);

        __asm__ volatile("s_waitcnt lgkmcnt(0)" ::: "memory");    // all my reads of buf[cur] done
        __builtin_amdgcn_s_barrier();                             // everyone done -> safe to overwrite
        cur ^= 1;
    }

    // epilogue: h = gelu(acc + b1'), partial logits = h @ w2 (3 cols), gated atomic add
    const int e = n0 >> 11;   // each 128-wide N-tile lies in one expert (H=2048)
    #pragma unroll
    for (int mi = 0; mi < 4; ++mi) {
        float pr[4][3];
        #pragma unroll
        for (int r = 0; r < 4; ++r) { pr[r][0] = 0.f; pr[r][1] = 0.f; pr[r][2] = 0.f; }
        #pragma unroll
        for (int ni = 0; ni < 4; ++ni) {
            const int nl = wn * 64 + ni * 16 + l15;
            const float b1v = b1s[nl];
            const float wa = w2s[nl * 3 + 0], wb = w2s[nl * 3 + 1], wc = w2s[nl * 3 + 2];
            #pragma unroll
            for (int r = 0; r < 4; ++r) {
                float xh = acc[mi][ni][r] + b1v;
                float h = gelu_fast(xh);
                pr[r][0] += h * wa; pr[r][1] += h * wb; pr[r][2] += h * wc;
            }
        }
        #pragma unroll
        for (int off = 1; off < 16; off <<= 1) {
            #pragma unroll
            for (int r = 0; r < 4; ++r) {
                pr[r][0] += __shfl_xor(pr[r][0], off);
                pr[r][1] += __shfl_xor(pr[r][1], off);
                pr[r][2] += __shfl_xor(pr[r][2], off);
            }
        }
        if (l15 == 0) {
            #pragma unroll
            for (int r = 0; r < 4; ++r) {
                const int row = m0 + wm * 64 + mi * 16 + quad * 4 + r;
                const float g = gate[(size_t)row * 4 + e];
                atomicAdd(&out[row * 3 + 0], g * pr[r][0]);
                atomicAdd(&out[row * 3 + 1], g * pr[r][1]);
                atomicAdd(&out[row * 3 + 2], g * pr[r][2]);
            }
        }
    }
}

// ---------- launch ----------
extern "C" void kernel_launch(void* const* d_in, const int* in_sizes, int n_in,
                              void* d_out, int out_size, void* d_ws, size_t ws_size,
                              hipStream_t stream) {
    const float* x     = (const float*)d_in[0];
    const float* gg    = (const float*)d_in[1];
    const float* gb    = (const float*)d_in[2];
    const float* gw    = (const float*)d_in[3];
    const float* gbias = (const float*)d_in[4];
    const float* exlng = (const float*)d_in[5];
    const float* exlnb = (const float*)d_in[6];
    const float* w1    = (const float*)d_in[7];
    const float* b1    = (const float*)d_in[8];
    const float* w2    = (const float*)d_in[9];
    const float* b2    = (const float*)d_in[10];
    float* out = (float*)d_out;

    char* ws = (char*)d_ws;
    unsigned short* normed = (unsigned short*)ws;                         // 16384*1024*2 = 33554432
    unsigned short* w1t    = (unsigned short*)(ws + 33554432);            // 8192*1024*2  = 16777216
    float* b1p  = (float*)(ws + 33554432 + 16777216);                     // 8192*4       = 32768
    float* gate = (float*)(ws + 33554432 + 16777216 + 32768);             // 16384*4*4    = 262144

    prep_w1<<<dim3(16, 32, 4), 256, 0, stream>>>(w1, exlng, w1t);
    prep_b1<<<dim3(32, 4), 256, 0, stream>>>(w1, exlnb, b1, b1p);
    norm_gate<<<16384, 256, 0, stream>>>(x, gg, gb, gw, gbias, b2, normed, gate, out);
    gemm_fused<<<dim3(128, 64), 256, 0, stream>>>(normed, w1t, b1p, w2, gate, out);
}

// Round 2
// 766.623 us; speedup vs baseline: 1.1700x; 1.0738x over previous
//
#include <hip/hip_runtime.h>
#include <hip/hip_bf16.h>

// ---------- helpers ----------
typedef __bf16 bf16x8 __attribute__((ext_vector_type(8)));
typedef float  f32x4  __attribute__((ext_vector_type(4)));

__device__ __forceinline__ unsigned short f2bf(float f) {
    union { float f; unsigned int u; } v; v.f = f;
    unsigned int u = v.u;
    unsigned int r = (u + 0x7fffu + ((u >> 16) & 1u)) >> 16;   // RNE
    return (unsigned short)r;
}

typedef const __attribute__((address_space(1))) unsigned int* gptr_t;
typedef __attribute__((address_space(3))) unsigned int* lptr_t;
__device__ __forceinline__ void async_ld16(const void* g, void* l) {
    __builtin_amdgcn_global_load_lds((gptr_t)g, (lptr_t)l, 16, 0, 0);
}

// fast GELU (tanh form): max |err| vs exact-erf GELU ~5e-4.
__device__ __forceinline__ float gelu_fast(float x) {
    const float c1 = 2.30223608f;          // 2*sqrt(2/pi)*log2(e)
    const float c2 = 0.102944903f;         // c1 * 0.044715
    float s  = x * x;
    float zn = x * __builtin_fmaf(s, -c2, -c1);
    float u  = __builtin_amdgcn_exp2f(zn);
    return x * __builtin_amdgcn_rcpf(1.0f + u);
}

#define Bn 16384
#define Dd 1024
#define Hh 2048
#define Ee 4
#define Cc 3

// ---------- kernel 1: W1' = diag(ex_ln_g) * W1, transposed to [N=E*H][K=D], bf16 ----------
__global__ void prep_w1(const float* __restrict__ w1, const float* __restrict__ exlng,
                        unsigned short* __restrict__ w1t) {
    __shared__ float tile[64][65];
    const int d0 = blockIdx.x * 64, h0 = blockIdx.y * 64, e = blockIdx.z;
    const int t = threadIdx.x;
    const float* gp = exlng + e * Dd + d0;
    const float* wp = w1 + ((size_t)e * Dd + d0) * Hh + h0;
    #pragma unroll
    for (int j = 0; j < 16; ++j) {
        int idx = t + j * 256; int dl = idx >> 6, hl = idx & 63;
        tile[dl][hl] = wp[(size_t)dl * Hh + hl] * gp[dl];
    }
    __syncthreads();
    #pragma unroll
    for (int j = 0; j < 8; ++j) {
        int idx = t + j * 256; int hl = idx >> 5, k2 = (idx & 31) * 2;
        ushort2 o; o.x = f2bf(tile[k2][hl]); o.y = f2bf(tile[k2 + 1][hl]);
        *(ushort2*)(w1t + ((size_t)(e * Hh + h0 + hl)) * Dd + d0 + k2) = o;
    }
}

// ---------- kernel 2: b1'[n] = b1[e][h] + sum_d ex_ln_b[e][d] * W1[e][d][h] ----------
__global__ void prep_b1(const float* __restrict__ w1, const float* __restrict__ exlnb,
                        const float* __restrict__ b1, float* __restrict__ b1p) {
    const int e = blockIdx.y, h0 = blockIdx.x * 64;
    const int t = threadIdx.x, hl = t & 63, dq = t >> 6;
    float acc = 0.f;
    const float* wp = w1 + ((size_t)e * Dd) * Hh + h0 + hl;
    const float* lb = exlnb + e * Dd;
    for (int d = dq; d < Dd; d += 4)
        acc += lb[d] * wp[(size_t)d * Hh];
    __shared__ float red[4][64];
    red[dq][hl] = acc;
    __syncthreads();
    if (t < 64) {
        float s = red[0][t] + red[1][t] + red[2][t] + red[3][t];
        b1p[e * Hh + h0 + t] = b1[e * Hh + h0 + t] + s;
    }
}

// ---------- kernel 3: normalize + gate softmax + out init ----------
__global__ void norm_gate(const float* __restrict__ x,
                          const float* __restrict__ gg, const float* __restrict__ gb,
                          const float* __restrict__ gw, const float* __restrict__ gbias,
                          const float* __restrict__ b2,
                          unsigned short* __restrict__ normed,
                          float* __restrict__ gate, float* __restrict__ out) {
    const int b = blockIdx.x, t = threadIdx.x, w = t >> 6, lane = t & 63;
    float4 xv = ((const float4*)(x + (size_t)b * Dd))[t];
    float s = xv.x + xv.y + xv.z + xv.w;
    float q = xv.x * xv.x + xv.y * xv.y + xv.z * xv.z + xv.w * xv.w;
    for (int off = 32; off; off >>= 1) { s += __shfl_down(s, off); q += __shfl_down(q, off); }
    __shared__ float rs[4], rq[4], lg[4][4];
    if (lane == 0) { rs[w] = s; rq[w] = q; }
    __syncthreads();
    s = rs[0] + rs[1] + rs[2] + rs[3];
    q = rq[0] + rq[1] + rq[2] + rq[3];
    const float mu = s * (1.f / Dd);
    const float var = q * (1.f / Dd) - mu * mu;
    const float rstd = rsqrtf(var + 1e-5f);
    float n0 = (xv.x - mu) * rstd, n1 = (xv.y - mu) * rstd,
          n2 = (xv.z - mu) * rstd, n3 = (xv.w - mu) * rstd;
    ushort4 u; u.x = f2bf(n0); u.y = f2bf(n1); u.z = f2bf(n2); u.w = f2bf(n3);
    ((ushort4*)(normed + (size_t)b * Dd))[t] = u;
    float4 g4 = ((const float4*)gg)[t], b4 = ((const float4*)gb)[t];
    float v0 = n0 * g4.x + b4.x, v1 = n1 * g4.y + b4.y,
          v2 = n2 * g4.z + b4.z, v3 = n3 * g4.w + b4.w;
    float4 w0 = ((const float4*)gw)[4 * t + 0], w1v = ((const float4*)gw)[4 * t + 1],
          w2v = ((const float4*)gw)[4 * t + 2], w3 = ((const float4*)gw)[4 * t + 3];
    float l0 = v0 * w0.x + v1 * w1v.x + v2 * w2v.x + v3 * w3.x;
    float l1 = v0 * w0.y + v1 * w1v.y + v2 * w2v.y + v3 * w3.y;
    float l2 = v0 * w0.z + v1 * w1v.z + v2 * w2v.z + v3 * w3.z;
    float l3 = v0 * w0.w + v1 * w1v.w + v2 * w2v.w + v3 * w3.w;
    for (int off = 32; off; off >>= 1) {
        l0 += __shfl_down(l0, off); l1 += __shfl_down(l1, off);
        l2 += __shfl_down(l2, off); l3 += __shfl_down(l3, off);
    }
    if (lane == 0) { lg[w][0] = l0; lg[w][1] = l1; lg[w][2] = l2; lg[w][3] = l3; }
    __syncthreads();
    if (t == 0) {
        float L0 = lg[0][0] + lg[1][0] + lg[2][0] + lg[3][0] + gbias[0];
        float L1 = lg[0][1] + lg[1][1] + lg[2][1] + lg[3][1] + gbias[1];
        float L2 = lg[0][2] + lg[1][2] + lg[2][2] + lg[3][2] + gbias[2];
        float L3 = lg[0][3] + lg[1][3] + lg[2][3] + lg[3][3] + gbias[3];
        float mx = fmaxf(fmaxf(L0, L1), fmaxf(L2, L3));
        float e0 = expf(L0 - mx), e1 = expf(L1 - mx), e2 = expf(L2 - mx), e3 = expf(L3 - mx);
        float inv = 1.f / (e0 + e1 + e2 + e3);
        float g0 = e0 * inv, g1 = e1 * inv, g2 = e2 * inv, g3 = e3 * inv;
        gate[b * 4 + 0] = g0; gate[b * 4 + 1] = g1;
        gate[b * 4 + 2] = g2; gate[b * 4 + 3] = g3;
        out[b * 3 + 0] = g0 * b2[0] + g1 * b2[3] + g2 * b2[6] + g3 * b2[9];
        out[b * 3 + 1] = g0 * b2[1] + g1 * b2[4] + g2 * b2[7] + g3 * b2[10];
        out[b * 3 + 2] = g0 * b2[2] + g1 * b2[5] + g2 * b2[8] + g3 * b2[11];
    }
}

// ---------- kernel 4: 256x256 deep-pipelined GEMM + GELU + (@W2) + gated atomic add ----------
// v3: 512 thr / 8 waves (2Mx4N, 128x64 per wave), BK=32, FOUR LDS buffers (2-tile prefetch
//     lead), counted vmcnt(4) at tile boundary (never 0 mid-loop), 2 phases x 16 MFMA per
//     tile with raw s_barrier + setprio(1) around MFMA. Swizzle identical to v2 (0-conflict).
__global__ __launch_bounds__(512, 2) void gemm_fused(
    const unsigned short* __restrict__ A,    // [16384][1024] bf16
    const unsigned short* __restrict__ Bt,   // [8192][1024] bf16 (N-major)
    const float* __restrict__ b1p,           // [8192]
    const float* __restrict__ w2,            // [8192][3]
    const float* __restrict__ gate,          // [16384][4]
    float* __restrict__ out)                 // [16384][3]
{
    __shared__ unsigned short As[4][256 * 32];   // 64 KB
    __shared__ unsigned short Bs[4][256 * 32];   // 64 KB
    __shared__ float w2s[256 * 3];
    __shared__ float b1s[256];

    const int m0 = blockIdx.x * 256;
    const int n0 = blockIdx.y * 256;
    const int t = threadIdx.x, lane = t & 63, wid = t >> 6;
    const int wm = wid >> 2, wn = wid & 3;          // 2 x 4 wave grid
    const int quad = lane >> 4, l15 = lane & 15;

    if (t < 256) {
        b1s[t] = b1p[n0 + t];
        w2s[t * 3 + 0] = w2[(n0 + t) * 3 + 0];
        w2s[t * 3 + 1] = w2[(n0 + t) * 3 + 1];
        w2s[t * 3 + 2] = w2[(n0 + t) * 3 + 2];
    }

    // staging: thread t -> row t>>2 (sweep adds 128), 16B slot (t&3), source col
    // pre-swizzled with ((row>>1)&3) so LDS[row][slot] = global[row][slot ^ ((row>>1)&3)].
    const int srow  = t >> 2;
    const int sslot = (t & 3) ^ ((t >> 3) & 3);
    const unsigned short* ga = A  + (size_t)(m0 + srow) * Dd + sslot * 8;
    const unsigned short* gb = Bt + (size_t)(n0 + srow) * Dd + sslot * 8;
    const int ldoff = t * 8;                        // elements; sweep 1 adds 4096

#define STAGE_A(kt) { unsigned short* d = &As[(kt) & 3][ldoff];                 \
    async_ld16(ga + (kt) * 32,            d);                                   \
    async_ld16(ga + (kt) * 32 + 128 * Dd, d + 4096); }
#define STAGE_B(kt) { unsigned short* d = &Bs[(kt) & 3][ldoff];                 \
    async_ld16(gb + (kt) * 32,            d);                                   \
    async_ld16(gb + (kt) * 32 + 128 * Dd, d + 4096); }

    f32x4 acc[8][4] = {};

    // fragment read offsets (elements), swizzled to match staging
    const int rsw   = (l15 >> 1) & 3;
    const int aBase = (wm * 128 + l15) * 32 + ((quad ^ rsw) * 8);
    const int bBase = (wn * 64  + l15) * 32 + ((quad ^ rsw) * 8);

    // prologue: stage tiles 0 and 1, wait for tile 0
    STAGE_A(0); STAGE_B(0);
    STAGE_A(1); STAGE_B(1);
    __asm__ volatile("s_waitcnt vmcnt(4)" ::: "memory");
    __syncthreads();

    for (int kt = 0; kt < 32; ++kt) {
        const unsigned short* as = &As[kt & 3][0];
        const unsigned short* bs = &Bs[kt & 3][0];

        // ---- phase 1: read B frags + A frags mi0-3, stage A of tile kt+2 ----
        bf16x8 bf[4], af[4];
        #pragma unroll
        for (int ni = 0; ni < 4; ++ni) bf[ni] = *(const bf16x8*)(bs + bBase + ni * 512);
        #pragma unroll
        for (int mi = 0; mi < 4; ++mi) af[mi] = *(const bf16x8*)(as + aBase + mi * 512);
        if (kt < 30) STAGE_A(kt + 2);
        __builtin_amdgcn_s_barrier();
        __asm__ volatile("s_waitcnt lgkmcnt(0)" ::: "memory");
        __builtin_amdgcn_s_setprio(1);
        #pragma unroll
        for (int mi = 0; mi < 4; ++mi)
            #pragma unroll
            for (int ni = 0; ni < 4; ++ni)
                acc[mi][ni] = __builtin_amdgcn_mfma_f32_16x16x32_bf16(af[mi], bf[ni], acc[mi][ni], 0, 0, 0);
        __builtin_amdgcn_s_setprio(0);
        __builtin_amdgcn_s_barrier();

        // ---- phase 2: read A frags mi4-7, stage B of tile kt+2, tile-boundary vmcnt ----
        bf16x8 af2[4];
        #pragma unroll
        for (int mi = 0; mi < 4; ++mi) af2[mi] = *(const bf16x8*)(as + aBase + 2048 + mi * 512);
        if (kt < 30) {
            STAGE_B(kt + 2);
            __asm__ volatile("s_waitcnt vmcnt(4)" ::: "memory");  // tile kt+1 landed; kt+2 in flight
        } else {
            __asm__ volatile("s_waitcnt vmcnt(0)" ::: "memory");  // epilogue tiles only
        }
        __builtin_amdgcn_s_barrier();
        __asm__ volatile("s_waitcnt lgkmcnt(0)" ::: "memory");
        __builtin_amdgcn_s_setprio(1);
        #pragma unroll
        for (int mi = 0; mi < 4; ++mi)
            #pragma unroll
            for (int ni = 0; ni < 4; ++ni)
                acc[mi + 4][ni] = __builtin_amdgcn_mfma_f32_16x16x32_bf16(af2[mi], bf[ni], acc[mi + 4][ni], 0, 0, 0);
        __builtin_amdgcn_s_setprio(0);
        __builtin_amdgcn_s_barrier();
    }
#undef STAGE_A
#undef STAGE_B

    // epilogue: h = gelu(acc + b1'), partial logits = h @ w2 (3 cols), gated atomic add
    const int e = n0 >> 11;   // each 256-wide N-tile lies in one expert (H=2048)
    #pragma unroll
    for (int mi = 0; mi < 8; ++mi) {
        float pr[4][3];
        #pragma unroll
        for (int r = 0; r < 4; ++r) { pr[r][0] = 0.f; pr[r][1] = 0.f; pr[r][2] = 0.f; }
        #pragma unroll
        for (int ni = 0; ni < 4; ++ni) {
            const int nl = wn * 64 + ni * 16 + l15;
            const float b1v = b1s[nl];
            const float wa = w2s[nl * 3 + 0], wb = w2s[nl * 3 + 1], wc = w2s[nl * 3 + 2];
            #pragma unroll
            for (int r = 0; r < 4; ++r) {
                float xh = acc[mi][ni][r] + b1v;
                float h = gelu_fast(xh);
                pr[r][0] += h * wa; pr[r][1] += h * wb; pr[r][2] += h * wc;
            }
        }
        #pragma unroll
        for (int off = 1; off < 16; off <<= 1) {
            #pragma unroll
            for (int r = 0; r < 4; ++r) {
                pr[r][0] += __shfl_xor(pr[r][0], off);
                pr[r][1] += __shfl_xor(pr[r][1], off);
                pr[r][2] += __shfl_xor(pr[r][2], off);
            }
        }
        if (l15 == 0) {
            #pragma unroll
            for (int r = 0; r < 4; ++r) {
                const int row = m0 + wm * 128 + mi * 16 + quad * 4 + r;
                const float g = gate[(size_t)row * 4 + e];
                atomicAdd(&out[row * 3 + 0], g * pr[r][0]);
                atomicAdd(&out[row * 3 + 1], g * pr[r][1]);
                atomicAdd(&out[row * 3 + 2], g * pr[r][2]);
            }
        }
    }
}

// ---------- launch ----------
extern "C" void kernel_launch(void* const* d_in, const int* in_sizes, int n_in,
                              void* d_out, int out_size, void* d_ws, size_t ws_size,
                              hipStream_t stream) {
    const float* x     = (const float*)d_in[0];
    const float* gg    = (const float*)d_in[1];
    const float* gb    = (const float*)d_in[2];
    const float* gw    = (const float*)d_in[3];
    const float* gbias = (const float*)d_in[4];
    const float* exlng = (const float*)d_in[5];
    const float* exlnb = (const float*)d_in[6];
    const float* w1    = (const float*)d_in[7];
    const float* b1    = (const float*)d_in[8];
    const float* w2    = (const float*)d_in[9];
    const float* b2    = (const float*)d_in[10];
    float* out = (float*)d_out;

    char* ws = (char*)d_ws;
    unsigned short* normed = (unsigned short*)ws;                         // 16384*1024*2 = 33554432
    unsigned short* w1t    = (unsigned short*)(ws + 33554432);            // 8192*1024*2  = 16777216
    float* b1p  = (float*)(ws + 33554432 + 16777216);                     // 8192*4       = 32768
    float* gate = (float*)(ws + 33554432 + 16777216 + 32768);             // 16384*4*4    = 262144

    prep_w1<<<dim3(16, 32, 4), 256, 0, stream>>>(w1, exlng, w1t);
    prep_b1<<<dim3(32, 4), 256, 0, stream>>>(w1, exlnb, b1, b1p);
    norm_gate<<<16384, 256, 0, stream>>>(x, gg, gb, gw, gbias, b2, normed, gate, out);
    gemm_fused<<<dim3(64, 32), 512, 0, stream>>>(normed, w1t, b1p, w2, gate, out);
}